// Round 11
// baseline (556.729 us; speedup 1.0000x reference)
//
#include <hip/hip_runtime.h>
#include <hip/hip_bf16.h>
#include <math.h>

#define D_MODEL 1024
#define NH 16
#define HD 64
#define TMAX 2048
#define DFF 4096
#define NB 64
#define ACS 256                 // attention chunk size (positions per block)
#define NC (TMAX / ACS)         // 8 chunks max

// ---- split-K GEMM partial, float4-n accumulation ----------------------------
// Thread owns 4 columns (n..n+3) x BPG batches. Per k-quad: 4 W float4 loads +
// BPG ds_read_b128 + 16*BPG FMAs  ->  16 FMA per ds_read (4x r6's ratio).
// NQ=16: 64-column tiles, BPG=4, same grid.x as r6's gemm64_part.
template<int KC, int NQ>
__global__ void gemm_part(const float* __restrict__ X,
                          const float* __restrict__ W,
                          float* __restrict__ P,
                          int K, int N) {
    constexpr int BPG = 64 * NQ / 256;          // batches per thread
    const int nq = threadIdx.x % NQ;
    const int bg = threadIdx.x / NQ;
    const int n  = blockIdx.x * NQ * 4 + nq * 4;
    const int k0 = blockIdx.y * KC;

    __shared__ float Xs[64][KC + 4];            // +4 pad: 2-way aliasing only (free)

    for (int idx = threadIdx.x; idx < 64 * (KC / 4); idx += 256) {
        const int b  = idx / (KC / 4);
        const int kk = (idx % (KC / 4)) * 4;
        *reinterpret_cast<float4*>(&Xs[b][kk]) =
            *reinterpret_cast<const float4*>(&X[(size_t)b * K + k0 + kk]);
    }
    __syncthreads();

    float4 acc[BPG];
#pragma unroll
    for (int i = 0; i < BPG; ++i) acc[i] = make_float4(0.f, 0.f, 0.f, 0.f);

    const float* Wp = W + (size_t)k0 * N + n;
#pragma unroll
    for (int kk = 0; kk < KC; kk += 4) {
        const float4 w0 = *reinterpret_cast<const float4*>(&Wp[(size_t)(kk+0) * N]);
        const float4 w1 = *reinterpret_cast<const float4*>(&Wp[(size_t)(kk+1) * N]);
        const float4 w2 = *reinterpret_cast<const float4*>(&Wp[(size_t)(kk+2) * N]);
        const float4 w3 = *reinterpret_cast<const float4*>(&Wp[(size_t)(kk+3) * N]);
#pragma unroll
        for (int i = 0; i < BPG; ++i) {
            const float4 xv = *reinterpret_cast<const float4*>(&Xs[bg * BPG + i][kk]);
            acc[i].x += xv.x*w0.x + xv.y*w1.x + xv.z*w2.x + xv.w*w3.x;
            acc[i].y += xv.x*w0.y + xv.y*w1.y + xv.z*w2.y + xv.w*w3.y;
            acc[i].z += xv.x*w0.z + xv.y*w1.z + xv.z*w2.z + xv.w*w3.z;
            acc[i].w += xv.x*w0.w + xv.y*w1.w + xv.z*w2.w + xv.w*w3.w;
        }
    }

    float* Pp = P + (size_t)blockIdx.y * 64 * N + n;
#pragma unroll
    for (int i = 0; i < BPG; ++i)
        *reinterpret_cast<float4*>(&Pp[(size_t)(bg * BPG + i) * N]) = acc[i];
}

// ---- reduce S partials + bias (+relu) -> Y[64,N] ----------------------------
template<bool RELU>
__global__ void reduce_kernel(const float* __restrict__ P,
                              const float* __restrict__ bias,
                              float* __restrict__ Y,
                              int N, int S) {
    const int i = blockIdx.x * 256 + threadIdx.x;   // over 64*N
    const int n = i % N;
    float s = 0.0f;
    for (int ss = 0; ss < S; ++ss)
        s += P[(size_t)ss * 64 * N + i];
    s += bias[n];
    if (RELU)  s = fmaxf(s, 0.0f);
    Y[i] = s;
}

// ---- fused: reduce S partials + bias + resid, then LayerNorm -> Y[64,1024] --
template<int S>
__global__ void reduce_ln_kernel(const float* __restrict__ P,
                                 const float* __restrict__ bias,
                                 const float* __restrict__ resid,
                                 const float* __restrict__ lnw,
                                 const float* __restrict__ lnb,
                                 float* __restrict__ Y) {
    const int b   = blockIdx.x;
    const int tid = threadIdx.x;
    float v[4];
    float s = 0.f, sq = 0.f;
#pragma unroll
    for (int jj = 0; jj < 4; ++jj) {
        const int n = jj * 256 + tid;
        float t = bias[n] + resid[(size_t)b * D_MODEL + n];
#pragma unroll
        for (int ss = 0; ss < S; ++ss)
            t += P[((size_t)ss * 64 + b) * D_MODEL + n];
        v[jj] = t; s += t; sq += t * t;
    }
    for (int off = 1; off < 64; off <<= 1) {
        s  += __shfl_xor(s, off);
        sq += __shfl_xor(sq, off);
    }
    __shared__ float rs[4], rq[4];
    const int wave = tid >> 6;
    if ((tid & 63) == 0) { rs[wave] = s; rq[wave] = sq; }
    __syncthreads();
    s  = rs[0] + rs[1] + rs[2] + rs[3];
    sq = rq[0] + rq[1] + rq[2] + rq[3];
    const float mean = s * (1.0f / D_MODEL);
    const float var  = sq * (1.0f / D_MODEL) - mean * mean;
    const float rstd = rsqrtf(var + 1e-5f);
#pragma unroll
    for (int jj = 0; jj < 4; ++jj) {
        const int n = jj * 256 + tid;
        Y[(size_t)b * D_MODEL + n] = (v[jj] - mean) * rstd * lnw[n] + lnb[n];
    }
}

// ---- flash-decode partial: one block per (b, h, chunk of 256) ---------------
// (round-6 verbatim — measured-best across r6..r10)
__global__ void attn_part(const float* __restrict__ qkv,
                          const float* __restrict__ k_cache,
                          const float* __restrict__ v_cache,
                          const int* __restrict__ kv_len,
                          float* __restrict__ m_ws,
                          float* __restrict__ s_ws,
                          float* __restrict__ o_ws) {
    const int b = blockIdx.x;
    const int h = blockIdx.y;
    const int c = blockIdx.z;
    const int tid = threadIdx.x; // 256

    const int L  = kv_len[b];
    const int nt = L + 1;
    const int c0 = c * ACS;
    if (c0 >= nt) return;                       // inactive chunk: no writes
    const int tend = min(ACS, nt - c0);
    const bool full = (c0 + ACS <= L);          // all 256 rows straight from cache

    __shared__ float q_s[HD];
    __shared__ float p_s[ACS];
    __shared__ float red[8];
    __shared__ float ored[16][HD + 4];

    const float* qkv_row = qkv + (size_t)b * (3 * D_MODEL);
    if (tid < HD) q_s[tid] = qkv_row[h * HD + tid] * 0.125f; // 1/sqrt(64)
    __syncthreads();

    const size_t bh = ((size_t)b * NH + h) * (size_t)TMAX * HD;
    const float* kc   = k_cache + bh + (size_t)c0 * HD;
    const float* vc   = v_cache + bh + (size_t)c0 * HD;
    const float* knew = qkv_row + D_MODEL     + h * HD;
    const float* vnew = qkv_row + 2 * D_MODEL + h * HD;
    const int Lloc = L - c0;

    // ---- scores: 16 lanes per row; rows rg, rg+16, ..., rg+240 ----
    const int rg = tid >> 4, l16 = tid & 15;
    const float4 qf = *reinterpret_cast<const float4*>(&q_s[l16 * 4]);
    if (full) {
        float4 kf[16];
#pragma unroll
        for (int j = 0; j < 16; ++j)
            kf[j] = *reinterpret_cast<const float4*>(&kc[(size_t)(rg + j * 16) * HD + l16 * 4]);
#pragma unroll
        for (int j = 0; j < 16; ++j) {
            float d = qf.x*kf[j].x + qf.y*kf[j].y + qf.z*kf[j].z + qf.w*kf[j].w;
            d += __shfl_xor(d, 1);
            d += __shfl_xor(d, 2);
            d += __shfl_xor(d, 4);
            d += __shfl_xor(d, 8);
            if (l16 == 0) p_s[rg + j * 16] = d;
        }
    } else {
        for (int t = rg; t < tend; t += 16) {
            const float* krow = (t == Lloc) ? knew : (kc + (size_t)t * HD);
            const float4 kf = *reinterpret_cast<const float4*>(&krow[l16 * 4]);
            float d = qf.x*kf.x + qf.y*kf.y + qf.z*kf.z + qf.w*kf.w;
            d += __shfl_xor(d, 1);
            d += __shfl_xor(d, 2);
            d += __shfl_xor(d, 4);
            d += __shfl_xor(d, 8);
            if (l16 == 0) p_s[t] = d;
        }
    }

    // ---- V prefetch to registers (independent of scores/softmax) ----
    const int d4 = tid & 15, r = tid >> 4;      // dim-quad, row-in-stride
    float4 vreg[16];
    if (full) {
#pragma unroll
        for (int j = 0; j < 16; ++j)
            vreg[j] = *reinterpret_cast<const float4*>(&vc[(size_t)(r + j * 16) * HD + d4 * 4]);
    } else {
#pragma unroll
        for (int j = 0; j < 16; ++j) {
            const int t = r + j * 16;
            if (t < tend) {
                const float* vrow = (t == Lloc) ? vnew : (vc + (size_t)t * HD);
                vreg[j] = *reinterpret_cast<const float4*>(&vrow[d4 * 4]);
            } else {
                vreg[j] = make_float4(0.f, 0.f, 0.f, 0.f);
            }
        }
    }
    __syncthreads();    // p_s complete

    // ---- softmax stats: exactly one element per thread ----
    const float pv = (tid < tend) ? p_s[tid] : -INFINITY;
    float m = pv;
    for (int off = 1; off < 64; off <<= 1) m = fmaxf(m, __shfl_xor(m, off));
    const int wave = tid >> 6;
    if ((tid & 63) == 0) red[wave] = m;
    __syncthreads();
    m = fmaxf(fmaxf(red[0], red[1]), fmaxf(red[2], red[3]));

    float e = (tid < tend) ? expf(pv - m) : 0.0f;
    p_s[tid] = e;                                // zero-fill beyond tend
    float s = e;
    for (int off = 1; off < 64; off <<= 1) s += __shfl_xor(s, off);
    if ((tid & 63) == 0) red[4 + wave] = s;
    __syncthreads();
    const float ssum = red[4] + red[5] + red[6] + red[7];

    // ---- unnormalized P@V from registers ----
    float4 acc = make_float4(0.f, 0.f, 0.f, 0.f);
#pragma unroll
    for (int j = 0; j < 16; ++j) {
        const float p = p_s[r + j * 16];
        acc.x += p * vreg[j].x; acc.y += p * vreg[j].y;
        acc.z += p * vreg[j].z; acc.w += p * vreg[j].w;
    }
    *reinterpret_cast<float4*>(&ored[r][d4 * 4]) = acc;
    __syncthreads();

    const size_t idx = ((size_t)b * NH + h) * NC + c;
    if (tid == 0) { m_ws[idx] = m; s_ws[idx] = ssum; }
    if (tid < HD) {
        float o = 0.0f;
#pragma unroll
        for (int g = 0; g < 16; ++g) o += ored[g][tid];
        o_ws[idx * HD + tid] = o;
    }
}

// ---- combine chunk partials -> o[b, h*HD + d] -------------------------------
__global__ void attn_combine(const float* __restrict__ m_ws,
                             const float* __restrict__ s_ws,
                             const float* __restrict__ o_ws,
                             const int* __restrict__ kv_len,
                             float* __restrict__ o) {
    const int b = blockIdx.x;
    const int h = blockIdx.y;
    const int d = threadIdx.x;  // 64
    const int nt = kv_len[b] + 1;
    const int nc = (nt + ACS - 1) / ACS;
    const size_t idx0 = ((size_t)b * NH + h) * NC;

    float M = -INFINITY;
    for (int c = 0; c < nc; ++c) M = fmaxf(M, m_ws[idx0 + c]);
    float den = 0.0f, num = 0.0f;
    for (int c = 0; c < nc; ++c) {
        const float w = expf(m_ws[idx0 + c] - M);
        den += w * s_ws[idx0 + c];
        num += w * o_ws[(idx0 + c) * HD + d];
    }
    o[(size_t)b * D_MODEL + h * HD + d] = num / den;
}

extern "C" void kernel_launch(void* const* d_in, const int* in_sizes, int n_in,
                              void* d_out, int out_size, void* d_ws, size_t ws_size,
                              hipStream_t stream) {
    const float* x       = (const float*)d_in[0];
    const float* k_cache = (const float*)d_in[1];
    const float* v_cache = (const float*)d_in[2];
    const int*   kv_len  = (const int*)d_in[4];
    const float* qkv_w   = (const float*)d_in[6];
    const float* qkv_b   = (const float*)d_in[7];
    const float* out_w   = (const float*)d_in[8];
    const float* out_b   = (const float*)d_in[9];
    const float* ln1_w   = (const float*)d_in[10];
    const float* ln1_b   = (const float*)d_in[11];
    const float* ln2_w   = (const float*)d_in[12];
    const float* ln2_b   = (const float*)d_in[13];
    const float* mlp_w1  = (const float*)d_in[14];
    const float* mlp_b1  = (const float*)d_in[15];
    const float* mlp_w2  = (const float*)d_in[16];
    const float* mlp_b2  = (const float*)d_in[17];

    float* out = (float*)d_out;
    float* ws  = (float*)d_ws;
    float* qkv = ws;                  // 64*3072 = 196608
    float* o   = ws + 196608;         // 64*1024
    float* t2  = ws + 262144;         // 64*1024
    float* t3  = ws + 327680;         // 64*4096
    float* P   = ws + 589824;         // split-K partials (up to 64 slabs)
    // attention partials alias P (disjoint in time):
    float* m_ws = P;                          // 64*16*8 = 8192
    float* s_ws = P + 8192;                   // 8192
    float* o_ws = P + 16384;                  // 8192*64 = 524288

    // ---- qkv = x @ qkv_w + qkv_b : K=1024, N=3072, KC=64 -> S=16 ----
    gemm_part<64, 16><<<dim3(48, 16), 256, 0, stream>>>(x, qkv_w, P, 1024, 3072);
    reduce_kernel<false><<<768, 256, 0, stream>>>(P, qkv_b, qkv, 3072, 16);

    // ---- attention (flash-decode over 8 chunks of 256) ----
    attn_part<<<dim3(NB, NH, NC), 256, 0, stream>>>(qkv, k_cache, v_cache, kv_len, m_ws, s_ws, o_ws);
    attn_combine<<<dim3(NB, NH), 64, 0, stream>>>(m_ws, s_ws, o_ws, kv_len, o);

    // ---- t2 = LN1(x + o @ out_w + out_b) : K=1024, N=1024, KC=64 -> S=16 ----
    gemm_part<64, 16><<<dim3(16, 16), 256, 0, stream>>>(o, out_w, P, 1024, 1024);
    reduce_ln_kernel<16><<<64, 256, 0, stream>>>(P, out_b, x, ln1_w, ln1_b, t2);

    // ---- t3 = relu(t2 @ mlp_w1 + mlp_b1) : K=1024, N=4096, KC=64 -> S=16 ----
    gemm_part<64, 16><<<dim3(64, 16), 256, 0, stream>>>(t2, mlp_w1, P, 1024, 4096);
    reduce_kernel<true><<<1024, 256, 0, stream>>>(P, mlp_b1, t3, 4096, 16);

    // ---- out = LN2(t2 + t3 @ mlp_w2 + mlp_b2) : K=4096, N=1024, KC=64 -> S=64
    gemm_part<64, 16><<<dim3(16, 64), 256, 0, stream>>>(t3, mlp_w2, P, 4096, 1024);
    reduce_ln_kernel<64><<<64, 256, 0, stream>>>(P, mlp_b2, t2, ln2_w, ln2_b, out);
}

// Round 12
// 293.838 us; speedup vs baseline: 1.8947x; 1.8947x over previous
//
#include <hip/hip_runtime.h>
#include <hip/hip_bf16.h>
#include <math.h>

#define D_MODEL 1024
#define NH 16
#define HD 64
#define TMAX 2048
#define DFF 4096
#define NB 64
#define ACS 256                 // attention chunk size (positions per block)
#define NC (TMAX / ACS)         // 8 chunks max
#define NPW (NC * 4)            // 32 wave-partials per (b,h)

// ---- split-K GEMM partial: P[s][64][N] = X[64, k0:k0+KC] @ W[k0:k0+KC, N] ----
// (round-6 verbatim — measured-good; r11's float4-n variant was 2x WORSE)
template<int KC>
__global__ void gemm64_part(const float* __restrict__ X,
                            const float* __restrict__ W,
                            float* __restrict__ P,
                            int K, int N) {
    const int tx = threadIdx.x & 63;
    const int ty = threadIdx.x >> 6;          // 0..3
    const int n  = blockIdx.x * 64 + tx;
    const int k0 = blockIdx.y * KC;

    __shared__ float Xs[64][KC];

    for (int idx = threadIdx.x; idx < 64 * (KC / 4); idx += 256) {
        const int b  = idx / (KC / 4);
        const int kk = (idx % (KC / 4)) * 4;
        *reinterpret_cast<float4*>(&Xs[b][kk]) =
            *reinterpret_cast<const float4*>(&X[(size_t)b * K + k0 + kk]);
    }
    __syncthreads();

    float acc[16] = {0.f,0.f,0.f,0.f,0.f,0.f,0.f,0.f,
                     0.f,0.f,0.f,0.f,0.f,0.f,0.f,0.f};
    const float* Wp = W + (size_t)k0 * N + n;
#pragma unroll
    for (int kk = 0; kk < KC; kk += 4) {
        const float w0 = Wp[(size_t)(kk+0) * N];
        const float w1 = Wp[(size_t)(kk+1) * N];
        const float w2 = Wp[(size_t)(kk+2) * N];
        const float w3 = Wp[(size_t)(kk+3) * N];
#pragma unroll
        for (int i = 0; i < 16; ++i) {
            const float4 xv = *reinterpret_cast<const float4*>(&Xs[ty*16 + i][kk]);
            acc[i] += xv.x*w0 + xv.y*w1 + xv.z*w2 + xv.w*w3;
        }
    }

    float* Pp = P + (size_t)blockIdx.y * 64 * N + n;
#pragma unroll
    for (int i = 0; i < 16; ++i)
        Pp[(size_t)(ty*16 + i) * N] = acc[i];
}

// ---- reduce S partials + bias (+relu) -> Y[64,N] ----------------------------
template<bool RELU>
__global__ void reduce_kernel(const float* __restrict__ P,
                              const float* __restrict__ bias,
                              float* __restrict__ Y,
                              int N, int S) {
    const int i = blockIdx.x * 256 + threadIdx.x;   // over 64*N
    const int n = i % N;
    float s = 0.0f;
    for (int ss = 0; ss < S; ++ss)
        s += P[(size_t)ss * 64 * N + i];
    s += bias[n];
    if (RELU)  s = fmaxf(s, 0.0f);
    Y[i] = s;
}

// ---- fused: reduce S partials + bias + resid, then LayerNorm -> Y[64,1024] --
template<int S>
__global__ void reduce_ln_kernel(const float* __restrict__ P,
                                 const float* __restrict__ bias,
                                 const float* __restrict__ resid,
                                 const float* __restrict__ lnw,
                                 const float* __restrict__ lnb,
                                 float* __restrict__ Y) {
    const int b   = blockIdx.x;
    const int tid = threadIdx.x;
    float v[4];
    float s = 0.f, sq = 0.f;
#pragma unroll
    for (int jj = 0; jj < 4; ++jj) {
        const int n = jj * 256 + tid;
        float t = bias[n] + resid[(size_t)b * D_MODEL + n];
#pragma unroll
        for (int ss = 0; ss < S; ++ss)
            t += P[((size_t)ss * 64 + b) * D_MODEL + n];
        v[jj] = t; s += t; sq += t * t;
    }
    for (int off = 1; off < 64; off <<= 1) {
        s  += __shfl_xor(s, off);
        sq += __shfl_xor(sq, off);
    }
    __shared__ float rs[4], rq[4];
    const int wave = tid >> 6;
    if ((tid & 63) == 0) { rs[wave] = s; rq[wave] = sq; }
    __syncthreads();
    s  = rs[0] + rs[1] + rs[2] + rs[3];
    sq = rq[0] + rq[1] + rq[2] + rq[3];
    const float mean = s * (1.0f / D_MODEL);
    const float var  = sq * (1.0f / D_MODEL) - mean * mean;
    const float rstd = rsqrtf(var + 1e-5f);
#pragma unroll
    for (int jj = 0; jj < 4; ++jj) {
        const int n = jj * 256 + tid;
        Y[(size_t)b * D_MODEL + n] = (v[jj] - mean) * rstd * lnw[n] + lnb[n];
    }
}

// ---- flash-decode partial, wave-autonomous: r6 memory pattern, NO barriers --
// Each wave owns rows {rg+16j} of the chunk; after the 4-step xor butterfly
// every lane holds the reduced score, so softmax+PV complete per-wave and the
// wave emits its own (m,s,o) partial. Zero LDS, zero __syncthreads.
__global__ void attn_part(const float* __restrict__ qkv,
                          const float* __restrict__ k_cache,
                          const float* __restrict__ v_cache,
                          const int* __restrict__ kv_len,
                          float* __restrict__ m_ws,
                          float* __restrict__ s_ws,
                          float* __restrict__ o_ws) {
    const int b = blockIdx.x;
    const int h = blockIdx.y;
    const int c = blockIdx.z;
    const int tid = threadIdx.x; // 256

    const int L  = kv_len[b];
    const int nt = L + 1;
    const int c0 = c * ACS;
    if (c0 >= nt) return;                       // inactive chunk: no writes
    const bool full = (c0 + ACS <= L);          // all 256 rows valid, from cache
    const int Lloc = L - c0;

    const int rg = tid >> 4, l16 = tid & 15;    // row-group (0..15), dim-quad
    const int wv = tid >> 6;

    const float* qkv_row = qkv + (size_t)b * (3 * D_MODEL);
    const float* knew = qkv_row + D_MODEL     + h * HD;
    const float* vnew = qkv_row + 2 * D_MODEL + h * HD;

    float4 qf = *reinterpret_cast<const float4*>(&qkv_row[h * HD + l16 * 4]);
    qf.x *= 0.125f; qf.y *= 0.125f; qf.z *= 0.125f; qf.w *= 0.125f;

    const size_t bh = ((size_t)b * NH + h) * (size_t)TMAX * HD;
    const float* kc = k_cache + bh + (size_t)c0 * HD;
    const float* vc = v_cache + bh + (size_t)c0 * HD;

    // ---- scores: r6's 16-deep K burst; d[j] reduced into ALL lanes ----
    float d[16];
    if (full) {
        float4 kf[16];
#pragma unroll
        for (int j = 0; j < 16; ++j)
            kf[j] = *reinterpret_cast<const float4*>(&kc[(size_t)(rg + j * 16) * HD + l16 * 4]);
#pragma unroll
        for (int j = 0; j < 16; ++j) {
            float sc = qf.x*kf[j].x + qf.y*kf[j].y + qf.z*kf[j].z + qf.w*kf[j].w;
            sc += __shfl_xor(sc, 1);
            sc += __shfl_xor(sc, 2);
            sc += __shfl_xor(sc, 4);
            sc += __shfl_xor(sc, 8);
            d[j] = sc;
        }
    } else {
#pragma unroll
        for (int j = 0; j < 16; ++j) {
            const int t = rg + j * 16;
            float sc = -INFINITY;
            if (t <= Lloc) {                    // uniform within the 16-lane group
                const float* krow = (t == Lloc) ? knew : (kc + (size_t)t * HD);
                const float4 kf = *reinterpret_cast<const float4*>(&krow[l16 * 4]);
                sc = qf.x*kf.x + qf.y*kf.y + qf.z*kf.z + qf.w*kf.w;
                sc += __shfl_xor(sc, 1);
                sc += __shfl_xor(sc, 2);
                sc += __shfl_xor(sc, 4);
                sc += __shfl_xor(sc, 8);
            }
            d[j] = sc;
        }
    }

    // ---- V burst (same rows as K: (rg, l16) mapping) ----
    float4 vreg[16];
    if (full) {
#pragma unroll
        for (int j = 0; j < 16; ++j)
            vreg[j] = *reinterpret_cast<const float4*>(&vc[(size_t)(rg + j * 16) * HD + l16 * 4]);
    } else {
#pragma unroll
        for (int j = 0; j < 16; ++j) {
            const int t = rg + j * 16;
            if (t <= Lloc) {
                const float* vrow = (t == Lloc) ? vnew : (vc + (size_t)t * HD);
                vreg[j] = *reinterpret_cast<const float4*>(&vrow[l16 * 4]);
            } else {
                vreg[j] = make_float4(0.f, 0.f, 0.f, 0.f);
            }
        }
    }

    // ---- wave-local softmax over this wave's 64 rows ----
    float m = d[0];
#pragma unroll
    for (int j = 1; j < 16; ++j) m = fmaxf(m, d[j]);
    m = fmaxf(m, __shfl_xor(m, 16));
    m = fmaxf(m, __shfl_xor(m, 32));
    m = fmaxf(m, -1.0e30f);                     // empty wave -> e=0, s=0 (valid)

    float s = 0.0f;
#pragma unroll
    for (int j = 0; j < 16; ++j) {
        d[j] = expf(d[j] - m);                  // -inf -> 0
        s += d[j];
    }
    s += __shfl_xor(s, 16);
    s += __shfl_xor(s, 32);

    // ---- unnormalized P@V, merged across the wave's 4 row-groups ----
    float4 acc = make_float4(0.f, 0.f, 0.f, 0.f);
#pragma unroll
    for (int j = 0; j < 16; ++j) {
        acc.x += d[j] * vreg[j].x; acc.y += d[j] * vreg[j].y;
        acc.z += d[j] * vreg[j].z; acc.w += d[j] * vreg[j].w;
    }
    acc.x += __shfl_xor(acc.x, 16); acc.y += __shfl_xor(acc.y, 16);
    acc.z += __shfl_xor(acc.z, 16); acc.w += __shfl_xor(acc.w, 16);
    acc.x += __shfl_xor(acc.x, 32); acc.y += __shfl_xor(acc.y, 32);
    acc.z += __shfl_xor(acc.z, 32); acc.w += __shfl_xor(acc.w, 32);

    const size_t idx = (((size_t)b * NH + h) * NC + c) * 4 + wv;
    if ((tid & 63) == 0) { m_ws[idx] = m; s_ws[idx] = s; }
    if (((tid >> 4) & 3) == 0)                  // first 16 lanes of the wave
        *reinterpret_cast<float4*>(&o_ws[idx * HD + l16 * 4]) = acc;
}

// ---- combine wave partials -> o[b, h*HD + d] --------------------------------
__global__ void attn_combine(const float* __restrict__ m_ws,
                             const float* __restrict__ s_ws,
                             const float* __restrict__ o_ws,
                             const int* __restrict__ kv_len,
                             float* __restrict__ o) {
    const int b = blockIdx.x;
    const int h = blockIdx.y;
    const int d = threadIdx.x;  // 64
    const int nt = kv_len[b] + 1;
    const int np = ((nt + ACS - 1) / ACS) * 4;  // wave partials present
    const size_t idx0 = ((size_t)b * NH + h) * NPW;

    float M = -INFINITY;
    for (int c = 0; c < np; ++c) M = fmaxf(M, m_ws[idx0 + c]);
    float den = 0.0f, num = 0.0f;
    for (int c = 0; c < np; ++c) {
        const float w = expf(m_ws[idx0 + c] - M);
        den += w * s_ws[idx0 + c];
        num += w * o_ws[(idx0 + c) * HD + d];
    }
    o[(size_t)b * D_MODEL + h * HD + d] = num / den;
}

extern "C" void kernel_launch(void* const* d_in, const int* in_sizes, int n_in,
                              void* d_out, int out_size, void* d_ws, size_t ws_size,
                              hipStream_t stream) {
    const float* x       = (const float*)d_in[0];
    const float* k_cache = (const float*)d_in[1];
    const float* v_cache = (const float*)d_in[2];
    const int*   kv_len  = (const int*)d_in[4];
    const float* qkv_w   = (const float*)d_in[6];
    const float* qkv_b   = (const float*)d_in[7];
    const float* out_w   = (const float*)d_in[8];
    const float* out_b   = (const float*)d_in[9];
    const float* ln1_w   = (const float*)d_in[10];
    const float* ln1_b   = (const float*)d_in[11];
    const float* ln2_w   = (const float*)d_in[12];
    const float* ln2_b   = (const float*)d_in[13];
    const float* mlp_w1  = (const float*)d_in[14];
    const float* mlp_b1  = (const float*)d_in[15];
    const float* mlp_w2  = (const float*)d_in[16];
    const float* mlp_b2  = (const float*)d_in[17];

    float* out = (float*)d_out;
    float* ws  = (float*)d_ws;
    float* qkv = ws;                  // 64*3072 = 196608
    float* o   = ws + 196608;         // 64*1024
    float* t2  = ws + 262144;         // 64*1024
    float* t3  = ws + 327680;         // 64*4096
    float* P   = ws + 589824;         // split-K partials (up to 64 slabs)
    // attention partials alias P (disjoint in time):
    float* m_ws = P;                          // 64*16*32 = 32768
    float* s_ws = P + 32768;                  // 32768
    float* o_ws = P + 65536;                  // 32768*64 = 2097152

    // ---- qkv = x @ qkv_w + qkv_b : K=1024, N=3072, KC=64 -> S=16 ----
    gemm64_part<64><<<dim3(48, 16), 256, 0, stream>>>(x, qkv_w, P, 1024, 3072);
    reduce_kernel<false><<<768, 256, 0, stream>>>(P, qkv_b, qkv, 3072, 16);

    // ---- attention (wave-autonomous flash-decode, 8 chunks x 4 waves) ----
    attn_part<<<dim3(NB, NH, NC), 256, 0, stream>>>(qkv, k_cache, v_cache, kv_len, m_ws, s_ws, o_ws);
    attn_combine<<<dim3(NB, NH), 64, 0, stream>>>(m_ws, s_ws, o_ws, kv_len, o);

    // ---- t2 = LN1(x + o @ out_w + out_b) : K=1024, N=1024, KC=64 -> S=16 ----
    gemm64_part<64><<<dim3(16, 16), 256, 0, stream>>>(o, out_w, P, 1024, 1024);
    reduce_ln_kernel<16><<<64, 256, 0, stream>>>(P, out_b, x, ln1_w, ln1_b, t2);

    // ---- t3 = relu(t2 @ mlp_w1 + mlp_b1) : K=1024, N=4096, KC=64 -> S=16 ----
    gemm64_part<64><<<dim3(64, 16), 256, 0, stream>>>(t2, mlp_w1, P, 1024, 4096);
    reduce_kernel<true><<<1024, 256, 0, stream>>>(P, mlp_b1, t3, 4096, 16);

    // ---- out = LN2(t2 + t3 @ mlp_w2 + mlp_b2) : K=4096, N=1024, KC=64 -> S=64
    gemm64_part<64><<<dim3(16, 64), 256, 0, stream>>>(t3, mlp_w2, P, 4096, 1024);
    reduce_ln_kernel<64><<<64, 256, 0, stream>>>(P, mlp_b2, t2, ln2_w, ln2_b, out);
}

// Round 14
// 250.349 us; speedup vs baseline: 2.2238x; 1.1737x over previous
//
#include <hip/hip_runtime.h>
#include <hip/hip_bf16.h>
#include <math.h>

#define D_MODEL 1024
#define NH 16
#define HD 64
#define TMAX 2048
#define DFF 4096
#define NB 64
#define ACS 256                 // attention chunk size (positions per block)
#define NC (TMAX / ACS)         // 8 chunks max

// non-temporal float4 load (evict-first; KV stream is never reused).
// __builtin_nontemporal_load needs a native clang vector type, not float4.
typedef float nat_f4 __attribute__((ext_vector_type(4)));
__device__ __forceinline__ float4 ldnt4(const float* p) {
    nat_f4 v = __builtin_nontemporal_load(reinterpret_cast<const nat_f4*>(p));
    return make_float4(v.x, v.y, v.z, v.w);
}

// ---- split-K GEMM partial: P[s][64][N] = X[64, k0:k0+KC] @ W[k0:k0+KC, N] ----
// (round-6 verbatim — measured-good)
template<int KC>
__global__ void gemm64_part(const float* __restrict__ X,
                            const float* __restrict__ W,
                            float* __restrict__ P,
                            int K, int N) {
    const int tx = threadIdx.x & 63;
    const int ty = threadIdx.x >> 6;          // 0..3
    const int n  = blockIdx.x * 64 + tx;
    const int k0 = blockIdx.y * KC;

    __shared__ float Xs[64][KC];

    for (int idx = threadIdx.x; idx < 64 * (KC / 4); idx += 256) {
        const int b  = idx / (KC / 4);
        const int kk = (idx % (KC / 4)) * 4;
        *reinterpret_cast<float4*>(&Xs[b][kk]) =
            *reinterpret_cast<const float4*>(&X[(size_t)b * K + k0 + kk]);
    }
    __syncthreads();

    float acc[16] = {0.f,0.f,0.f,0.f,0.f,0.f,0.f,0.f,
                     0.f,0.f,0.f,0.f,0.f,0.f,0.f,0.f};
    const float* Wp = W + (size_t)k0 * N + n;
#pragma unroll
    for (int kk = 0; kk < KC; kk += 4) {
        const float w0 = Wp[(size_t)(kk+0) * N];
        const float w1 = Wp[(size_t)(kk+1) * N];
        const float w2 = Wp[(size_t)(kk+2) * N];
        const float w3 = Wp[(size_t)(kk+3) * N];
#pragma unroll
        for (int i = 0; i < 16; ++i) {
            const float4 xv = *reinterpret_cast<const float4*>(&Xs[ty*16 + i][kk]);
            acc[i] += xv.x*w0 + xv.y*w1 + xv.z*w2 + xv.w*w3;
        }
    }

    float* Pp = P + (size_t)blockIdx.y * 64 * N + n;
#pragma unroll
    for (int i = 0; i < 16; ++i)
        Pp[(size_t)(ty*16 + i) * N] = acc[i];
}

// ---- reduce S partials + bias (+relu) -> Y[64,N] ----------------------------
template<bool RELU>
__global__ void reduce_kernel(const float* __restrict__ P,
                              const float* __restrict__ bias,
                              float* __restrict__ Y,
                              int N, int S) {
    const int i = blockIdx.x * 256 + threadIdx.x;   // over 64*N
    const int n = i % N;
    float s = 0.0f;
    for (int ss = 0; ss < S; ++ss)
        s += P[(size_t)ss * 64 * N + i];
    s += bias[n];
    if (RELU)  s = fmaxf(s, 0.0f);
    Y[i] = s;
}

// ---- fused: reduce S partials + bias + resid, then LayerNorm -> Y[64,1024] --
template<int S>
__global__ void reduce_ln_kernel(const float* __restrict__ P,
                                 const float* __restrict__ bias,
                                 const float* __restrict__ resid,
                                 const float* __restrict__ lnw,
                                 const float* __restrict__ lnb,
                                 float* __restrict__ Y) {
    const int b   = blockIdx.x;
    const int tid = threadIdx.x;
    float v[4];
    float s = 0.f, sq = 0.f;
#pragma unroll
    for (int jj = 0; jj < 4; ++jj) {
        const int n = jj * 256 + tid;
        float t = bias[n] + resid[(size_t)b * D_MODEL + n];
#pragma unroll
        for (int ss = 0; ss < S; ++ss)
            t += P[((size_t)ss * 64 + b) * D_MODEL + n];
        v[jj] = t; s += t; sq += t * t;
    }
    for (int off = 1; off < 64; off <<= 1) {
        s  += __shfl_xor(s, off);
        sq += __shfl_xor(sq, off);
    }
    __shared__ float rs[4], rq[4];
    const int wave = tid >> 6;
    if ((tid & 63) == 0) { rs[wave] = s; rq[wave] = sq; }
    __syncthreads();
    s  = rs[0] + rs[1] + rs[2] + rs[3];
    sq = rq[0] + rq[1] + rq[2] + rq[3];
    const float mean = s * (1.0f / D_MODEL);
    const float var  = sq * (1.0f / D_MODEL) - mean * mean;
    const float rstd = rsqrtf(var + 1e-5f);
#pragma unroll
    for (int jj = 0; jj < 4; ++jj) {
        const int n = jj * 256 + tid;
        Y[(size_t)b * D_MODEL + n] = (v[jj] - mean) * rstd * lnw[n] + lnb[n];
    }
}

// ---- flash-decode partial: one block per (b, h, chunk of 256) ---------------
// (round-6 verbatim, except kc/vc loads are NON-TEMPORAL: the 800 MB/iter KV
// stream is read-once — evict-first keeps it from flushing weights out of L3.)
__global__ void attn_part(const float* __restrict__ qkv,
                          const float* __restrict__ k_cache,
                          const float* __restrict__ v_cache,
                          const int* __restrict__ kv_len,
                          float* __restrict__ m_ws,
                          float* __restrict__ s_ws,
                          float* __restrict__ o_ws) {
    const int b = blockIdx.x;
    const int h = blockIdx.y;
    const int c = blockIdx.z;
    const int tid = threadIdx.x; // 256

    const int L  = kv_len[b];
    const int nt = L + 1;
    const int c0 = c * ACS;
    if (c0 >= nt) return;                       // inactive chunk: no writes
    const int tend = min(ACS, nt - c0);
    const bool full = (c0 + ACS <= L);          // all 256 rows straight from cache

    __shared__ float q_s[HD];
    __shared__ float p_s[ACS];
    __shared__ float red[8];
    __shared__ float ored[16][HD + 4];

    const float* qkv_row = qkv + (size_t)b * (3 * D_MODEL);
    if (tid < HD) q_s[tid] = qkv_row[h * HD + tid] * 0.125f; // 1/sqrt(64)
    __syncthreads();

    const size_t bh = ((size_t)b * NH + h) * (size_t)TMAX * HD;
    const float* kc   = k_cache + bh + (size_t)c0 * HD;
    const float* vc   = v_cache + bh + (size_t)c0 * HD;
    const float* knew = qkv_row + D_MODEL     + h * HD;
    const float* vnew = qkv_row + 2 * D_MODEL + h * HD;
    const int Lloc = L - c0;

    // ---- scores: 16 lanes per row; rows rg, rg+16, ..., rg+240 ----
    const int rg = tid >> 4, l16 = tid & 15;
    const float4 qf = *reinterpret_cast<const float4*>(&q_s[l16 * 4]);
    if (full) {
        float4 kf[16];
#pragma unroll
        for (int j = 0; j < 16; ++j)
            kf[j] = ldnt4(&kc[(size_t)(rg + j * 16) * HD + l16 * 4]);
#pragma unroll
        for (int j = 0; j < 16; ++j) {
            float d = qf.x*kf[j].x + qf.y*kf[j].y + qf.z*kf[j].z + qf.w*kf[j].w;
            d += __shfl_xor(d, 1);
            d += __shfl_xor(d, 2);
            d += __shfl_xor(d, 4);
            d += __shfl_xor(d, 8);
            if (l16 == 0) p_s[rg + j * 16] = d;
        }
    } else {
        for (int t = rg; t < tend; t += 16) {
            const float4 kf = (t == Lloc)
                ? *reinterpret_cast<const float4*>(&knew[l16 * 4])
                : ldnt4(&kc[(size_t)t * HD + l16 * 4]);
            float d = qf.x*kf.x + qf.y*kf.y + qf.z*kf.z + qf.w*kf.w;
            d += __shfl_xor(d, 1);
            d += __shfl_xor(d, 2);
            d += __shfl_xor(d, 4);
            d += __shfl_xor(d, 8);
            if (l16 == 0) p_s[t] = d;
        }
    }

    // ---- V prefetch to registers (independent of scores/softmax) ----
    const int d4 = tid & 15, r = tid >> 4;      // dim-quad, row-in-stride
    float4 vreg[16];
    if (full) {
#pragma unroll
        for (int j = 0; j < 16; ++j)
            vreg[j] = ldnt4(&vc[(size_t)(r + j * 16) * HD + d4 * 4]);
    } else {
#pragma unroll
        for (int j = 0; j < 16; ++j) {
            const int t = r + j * 16;
            if (t < tend) {
                vreg[j] = (t == Lloc)
                    ? *reinterpret_cast<const float4*>(&vnew[d4 * 4])
                    : ldnt4(&vc[(size_t)t * HD + d4 * 4]);
            } else {
                vreg[j] = make_float4(0.f, 0.f, 0.f, 0.f);
            }
        }
    }
    __syncthreads();    // p_s complete

    // ---- softmax stats: exactly one element per thread ----
    const float pv = (tid < tend) ? p_s[tid] : -INFINITY;
    float m = pv;
    for (int off = 1; off < 64; off <<= 1) m = fmaxf(m, __shfl_xor(m, off));
    const int wave = tid >> 6;
    if ((tid & 63) == 0) red[wave] = m;
    __syncthreads();
    m = fmaxf(fmaxf(red[0], red[1]), fmaxf(red[2], red[3]));

    float e = (tid < tend) ? expf(pv - m) : 0.0f;
    p_s[tid] = e;                                // zero-fill beyond tend
    float s = e;
    for (int off = 1; off < 64; off <<= 1) s += __shfl_xor(s, off);
    if ((tid & 63) == 0) red[4 + wave] = s;
    __syncthreads();
    const float ssum = red[4] + red[5] + red[6] + red[7];

    // ---- unnormalized P@V from registers ----
    float4 acc = make_float4(0.f, 0.f, 0.f, 0.f);
#pragma unroll
    for (int j = 0; j < 16; ++j) {
        const float p = p_s[r + j * 16];
        acc.x += p * vreg[j].x; acc.y += p * vreg[j].y;
        acc.z += p * vreg[j].z; acc.w += p * vreg[j].w;
    }
    *reinterpret_cast<float4*>(&ored[r][d4 * 4]) = acc;
    __syncthreads();

    const size_t idx = ((size_t)b * NH + h) * NC + c;
    if (tid == 0) { m_ws[idx] = m; s_ws[idx] = ssum; }
    if (tid < HD) {
        float o = 0.0f;
#pragma unroll
        for (int g = 0; g < 16; ++g) o += ored[g][tid];
        o_ws[idx * HD + tid] = o;
    }
}

// ---- combine chunk partials -> o[b, h*HD + d] -------------------------------
__global__ void attn_combine(const float* __restrict__ m_ws,
                             const float* __restrict__ s_ws,
                             const float* __restrict__ o_ws,
                             const int* __restrict__ kv_len,
                             float* __restrict__ o) {
    const int b = blockIdx.x;
    const int h = blockIdx.y;
    const int d = threadIdx.x;  // 64
    const int nt = kv_len[b] + 1;
    const int nc = (nt + ACS - 1) / ACS;
    const size_t idx0 = ((size_t)b * NH + h) * NC;

    float M = -INFINITY;
    for (int c = 0; c < nc; ++c) M = fmaxf(M, m_ws[idx0 + c]);
    float den = 0.0f, num = 0.0f;
    for (int c = 0; c < nc; ++c) {
        const float w = expf(m_ws[idx0 + c] - M);
        den += w * s_ws[idx0 + c];
        num += w * o_ws[(idx0 + c) * HD + d];
    }
    o[(size_t)b * D_MODEL + h * HD + d] = num / den;
}

extern "C" void kernel_launch(void* const* d_in, const int* in_sizes, int n_in,
                              void* d_out, int out_size, void* d_ws, size_t ws_size,
                              hipStream_t stream) {
    const float* x       = (const float*)d_in[0];
    const float* k_cache = (const float*)d_in[1];
    const float* v_cache = (const float*)d_in[2];
    const int*   kv_len  = (const int*)d_in[4];
    const float* qkv_w   = (const float*)d_in[6];
    const float* qkv_b   = (const float*)d_in[7];
    const float* out_w   = (const float*)d_in[8];
    const float* out_b   = (const float*)d_in[9];
    const float* ln1_w   = (const float*)d_in[10];
    const float* ln1_b   = (const float*)d_in[11];
    const float* ln2_w   = (const float*)d_in[12];
    const float* ln2_b   = (const float*)d_in[13];
    const float* mlp_w1  = (const float*)d_in[14];
    const float* mlp_b1  = (const float*)d_in[15];
    const float* mlp_w2  = (const float*)d_in[16];
    const float* mlp_b2  = (const float*)d_in[17];

    float* out = (float*)d_out;
    float* ws  = (float*)d_ws;
    float* qkv = ws;                  // 64*3072 = 196608
    float* o   = ws + 196608;         // 64*1024
    float* t2  = ws + 262144;         // 64*1024
    float* t3  = ws + 327680;         // 64*4096
    float* P   = ws + 589824;         // split-K partials (up to 64 slabs)
    // attention partials alias P (disjoint in time):
    float* m_ws = P;                          // 64*16*8 = 8192
    float* s_ws = P + 8192;                   // 8192
    float* o_ws = P + 16384;                  // 8192*64 = 524288

    // ---- qkv = x @ qkv_w + qkv_b : K=1024, N=3072, KC=64 -> S=16 ----
    gemm64_part<64><<<dim3(48, 16), 256, 0, stream>>>(x, qkv_w, P, 1024, 3072);
    reduce_kernel<false><<<768, 256, 0, stream>>>(P, qkv_b, qkv, 3072, 16);

    // ---- attention (flash-decode over 8 chunks of 256) ----
    attn_part<<<dim3(NB, NH, NC), 256, 0, stream>>>(qkv, k_cache, v_cache, kv_len, m_ws, s_ws, o_ws);
    attn_combine<<<dim3(NB, NH), 64, 0, stream>>>(m_ws, s_ws, o_ws, kv_len, o);

    // ---- t2 = LN1(x + o @ out_w + out_b) : K=1024, N=1024, KC=64 -> S=16 ----
    gemm64_part<64><<<dim3(16, 16), 256, 0, stream>>>(o, out_w, P, 1024, 1024);
    reduce_ln_kernel<16><<<64, 256, 0, stream>>>(P, out_b, x, ln1_w, ln1_b, t2);

    // ---- t3 = relu(t2 @ mlp_w1 + mlp_b1) : K=1024, N=4096, KC=64 -> S=16 ----
    gemm64_part<64><<<dim3(64, 16), 256, 0, stream>>>(t2, mlp_w1, P, 1024, 4096);
    reduce_kernel<true><<<1024, 256, 0, stream>>>(P, mlp_b1, t3, 4096, 16);

    // ---- out = LN2(t2 + t3 @ mlp_w2 + mlp_b2) : K=4096, N=1024, KC=64 -> S=64
    gemm64_part<64><<<dim3(16, 64), 256, 0, stream>>>(t3, mlp_w2, P, 4096, 1024);
    reduce_ln_kernel<64><<<64, 256, 0, stream>>>(P, mlp_b2, t2, ln2_w, ln2_b, out);
}

// Round 15
// 226.572 us; speedup vs baseline: 2.4572x; 1.1049x over previous
//
#include <hip/hip_runtime.h>
#include <hip/hip_bf16.h>
#include <math.h>

#define D_MODEL 1024
#define NH 16
#define HD 64
#define TMAX 2048
#define DFF 4096
#define NB 64
#define ACS 256                 // attention chunk size (positions per block)
#define NC (TMAX / ACS)         // 8 chunks max

// non-temporal float4 load (evict-first; KV stream is never reused).
typedef float nat_f4 __attribute__((ext_vector_type(4)));
__device__ __forceinline__ float4 ldnt4(const float* p) {
    nat_f4 v = __builtin_nontemporal_load(reinterpret_cast<const nat_f4*>(p));
    return make_float4(v.x, v.y, v.z, v.w);
}

// ---- split-K GEMM partial: P[s][64][N] = X[64, k0:k0+KC] @ W[k0:k0+KC, N] ----
// fully unrolled K-loop (r6 mechanism); KC=128 doubles per-block depth.
template<int KC>
__global__ void gemm64_part(const float* __restrict__ X,
                            const float* __restrict__ W,
                            float* __restrict__ P,
                            int K, int N) {
    const int tx = threadIdx.x & 63;
    const int ty = threadIdx.x >> 6;          // 0..3
    const int n  = blockIdx.x * 64 + tx;
    const int k0 = blockIdx.y * KC;

    __shared__ float Xs[64][KC];

    for (int idx = threadIdx.x; idx < 64 * (KC / 4); idx += 256) {
        const int b  = idx / (KC / 4);
        const int kk = (idx % (KC / 4)) * 4;
        *reinterpret_cast<float4*>(&Xs[b][kk]) =
            *reinterpret_cast<const float4*>(&X[(size_t)b * K + k0 + kk]);
    }
    __syncthreads();

    float acc[16] = {0.f,0.f,0.f,0.f,0.f,0.f,0.f,0.f,
                     0.f,0.f,0.f,0.f,0.f,0.f,0.f,0.f};
    const float* Wp = W + (size_t)k0 * N + n;
#pragma unroll
    for (int kk = 0; kk < KC; kk += 4) {
        const float w0 = Wp[(size_t)(kk+0) * N];
        const float w1 = Wp[(size_t)(kk+1) * N];
        const float w2 = Wp[(size_t)(kk+2) * N];
        const float w3 = Wp[(size_t)(kk+3) * N];
#pragma unroll
        for (int i = 0; i < 16; ++i) {
            const float4 xv = *reinterpret_cast<const float4*>(&Xs[ty*16 + i][kk]);
            acc[i] += xv.x*w0 + xv.y*w1 + xv.z*w2 + xv.w*w3;
        }
    }

    float* Pp = P + (size_t)blockIdx.y * 64 * N + n;
#pragma unroll
    for (int i = 0; i < 16; ++i)
        Pp[(size_t)(ty*16 + i) * N] = acc[i];
}

// ---- reduce S partials + bias (+relu) -> Y[64,N] ----------------------------
template<bool RELU>
__global__ void reduce_kernel(const float* __restrict__ P,
                              const float* __restrict__ bias,
                              float* __restrict__ Y,
                              int N, int S) {
    const int i = blockIdx.x * 256 + threadIdx.x;   // over 64*N
    const int n = i % N;
    float s = 0.0f;
    for (int ss = 0; ss < S; ++ss)
        s += P[(size_t)ss * 64 * N + i];
    s += bias[n];
    if (RELU)  s = fmaxf(s, 0.0f);
    Y[i] = s;
}

// ---- fused: reduce S partials + bias + resid, then LayerNorm -> Y[64,1024] --
template<int S>
__global__ void reduce_ln_kernel(const float* __restrict__ P,
                                 const float* __restrict__ bias,
                                 const float* __restrict__ resid,
                                 const float* __restrict__ lnw,
                                 const float* __restrict__ lnb,
                                 float* __restrict__ Y) {
    const int b   = blockIdx.x;
    const int tid = threadIdx.x;
    float v[4];
    float s = 0.f, sq = 0.f;
#pragma unroll
    for (int jj = 0; jj < 4; ++jj) {
        const int n = jj * 256 + tid;
        float t = bias[n] + resid[(size_t)b * D_MODEL + n];
#pragma unroll
        for (int ss = 0; ss < S; ++ss)
            t += P[((size_t)ss * 64 + b) * D_MODEL + n];
        v[jj] = t; s += t; sq += t * t;
    }
    for (int off = 1; off < 64; off <<= 1) {
        s  += __shfl_xor(s, off);
        sq += __shfl_xor(sq, off);
    }
    __shared__ float rs[4], rq[4];
    const int wave = tid >> 6;
    if ((tid & 63) == 0) { rs[wave] = s; rq[wave] = sq; }
    __syncthreads();
    s  = rs[0] + rs[1] + rs[2] + rs[3];
    sq = rq[0] + rq[1] + rq[2] + rq[3];
    const float mean = s * (1.0f / D_MODEL);
    const float var  = sq * (1.0f / D_MODEL) - mean * mean;
    const float rstd = rsqrtf(var + 1e-5f);
#pragma unroll
    for (int jj = 0; jj < 4; ++jj) {
        const int n = jj * 256 + tid;
        Y[(size_t)b * D_MODEL + n] = (v[jj] - mean) * rstd * lnw[n] + lnb[n];
    }
}

// ---- flash-decode partial: one block per (b, h, chunk of 256) ---------------
// (round-14 verbatim — measured-good: NT loads on KV stream)
__global__ void attn_part(const float* __restrict__ qkv,
                          const float* __restrict__ k_cache,
                          const float* __restrict__ v_cache,
                          const int* __restrict__ kv_len,
                          float* __restrict__ m_ws,
                          float* __restrict__ s_ws,
                          float* __restrict__ o_ws) {
    const int b = blockIdx.x;
    const int h = blockIdx.y;
    const int c = blockIdx.z;
    const int tid = threadIdx.x; // 256

    const int L  = kv_len[b];
    const int nt = L + 1;
    const int c0 = c * ACS;
    if (c0 >= nt) return;                       // inactive chunk: no writes
    const int tend = min(ACS, nt - c0);
    const bool full = (c0 + ACS <= L);          // all 256 rows straight from cache

    __shared__ float q_s[HD];
    __shared__ float p_s[ACS];
    __shared__ float red[8];
    __shared__ float ored[16][HD + 4];

    const float* qkv_row = qkv + (size_t)b * (3 * D_MODEL);
    if (tid < HD) q_s[tid] = qkv_row[h * HD + tid] * 0.125f; // 1/sqrt(64)
    __syncthreads();

    const size_t bh = ((size_t)b * NH + h) * (size_t)TMAX * HD;
    const float* kc   = k_cache + bh + (size_t)c0 * HD;
    const float* vc   = v_cache + bh + (size_t)c0 * HD;
    const float* knew = qkv_row + D_MODEL     + h * HD;
    const float* vnew = qkv_row + 2 * D_MODEL + h * HD;
    const int Lloc = L - c0;

    // ---- scores: 16 lanes per row; rows rg, rg+16, ..., rg+240 ----
    const int rg = tid >> 4, l16 = tid & 15;
    const float4 qf = *reinterpret_cast<const float4*>(&q_s[l16 * 4]);
    if (full) {
        float4 kf[16];
#pragma unroll
        for (int j = 0; j < 16; ++j)
            kf[j] = ldnt4(&kc[(size_t)(rg + j * 16) * HD + l16 * 4]);
#pragma unroll
        for (int j = 0; j < 16; ++j) {
            float d = qf.x*kf[j].x + qf.y*kf[j].y + qf.z*kf[j].z + qf.w*kf[j].w;
            d += __shfl_xor(d, 1);
            d += __shfl_xor(d, 2);
            d += __shfl_xor(d, 4);
            d += __shfl_xor(d, 8);
            if (l16 == 0) p_s[rg + j * 16] = d;
        }
    } else {
        for (int t = rg; t < tend; t += 16) {
            const float4 kf = (t == Lloc)
                ? *reinterpret_cast<const float4*>(&knew[l16 * 4])
                : ldnt4(&kc[(size_t)t * HD + l16 * 4]);
            float d = qf.x*kf.x + qf.y*kf.y + qf.z*kf.z + qf.w*kf.w;
            d += __shfl_xor(d, 1);
            d += __shfl_xor(d, 2);
            d += __shfl_xor(d, 4);
            d += __shfl_xor(d, 8);
            if (l16 == 0) p_s[t] = d;
        }
    }

    // ---- V prefetch to registers (independent of scores/softmax) ----
    const int d4 = tid & 15, r = tid >> 4;      // dim-quad, row-in-stride
    float4 vreg[16];
    if (full) {
#pragma unroll
        for (int j = 0; j < 16; ++j)
            vreg[j] = ldnt4(&vc[(size_t)(r + j * 16) * HD + d4 * 4]);
    } else {
#pragma unroll
        for (int j = 0; j < 16; ++j) {
            const int t = r + j * 16;
            if (t < tend) {
                vreg[j] = (t == Lloc)
                    ? *reinterpret_cast<const float4*>(&vnew[d4 * 4])
                    : ldnt4(&vc[(size_t)t * HD + d4 * 4]);
            } else {
                vreg[j] = make_float4(0.f, 0.f, 0.f, 0.f);
            }
        }
    }
    __syncthreads();    // p_s complete

    // ---- softmax stats: exactly one element per thread ----
    const float pv = (tid < tend) ? p_s[tid] : -INFINITY;
    float m = pv;
    for (int off = 1; off < 64; off <<= 1) m = fmaxf(m, __shfl_xor(m, off));
    const int wave = tid >> 6;
    if ((tid & 63) == 0) red[wave] = m;
    __syncthreads();
    m = fmaxf(fmaxf(red[0], red[1]), fmaxf(red[2], red[3]));

    float e = (tid < tend) ? expf(pv - m) : 0.0f;
    p_s[tid] = e;                                // zero-fill beyond tend
    float s = e;
    for (int off = 1; off < 64; off <<= 1) s += __shfl_xor(s, off);
    if ((tid & 63) == 0) red[4 + wave] = s;
    __syncthreads();
    const float ssum = red[4] + red[5] + red[6] + red[7];

    // ---- unnormalized P@V from registers ----
    float4 acc = make_float4(0.f, 0.f, 0.f, 0.f);
#pragma unroll
    for (int j = 0; j < 16; ++j) {
        const float p = p_s[r + j * 16];
        acc.x += p * vreg[j].x; acc.y += p * vreg[j].y;
        acc.z += p * vreg[j].z; acc.w += p * vreg[j].w;
    }
    *reinterpret_cast<float4*>(&ored[r][d4 * 4]) = acc;
    __syncthreads();

    const size_t idx = ((size_t)b * NH + h) * NC + c;
    if (tid == 0) { m_ws[idx] = m; s_ws[idx] = ssum; }
    if (tid < HD) {
        float o = 0.0f;
#pragma unroll
        for (int g = 0; g < 16; ++g) o += ored[g][tid];
        o_ws[idx * HD + tid] = o;
    }
}

// ---- combine chunk partials -> o[b, h*HD + d] -------------------------------
__global__ void attn_combine(const float* __restrict__ m_ws,
                             const float* __restrict__ s_ws,
                             const float* __restrict__ o_ws,
                             const int* __restrict__ kv_len,
                             float* __restrict__ o) {
    const int b = blockIdx.x;
    const int h = blockIdx.y;
    const int d = threadIdx.x;  // 64
    const int nt = kv_len[b] + 1;
    const int nc = (nt + ACS - 1) / ACS;
    const size_t idx0 = ((size_t)b * NH + h) * NC;

    float M = -INFINITY;
    for (int c = 0; c < nc; ++c) M = fmaxf(M, m_ws[idx0 + c]);
    float den = 0.0f, num = 0.0f;
    for (int c = 0; c < nc; ++c) {
        const float w = expf(m_ws[idx0 + c] - M);
        den += w * s_ws[idx0 + c];
        num += w * o_ws[(idx0 + c) * HD + d];
    }
    o[(size_t)b * D_MODEL + h * HD + d] = num / den;
}

extern "C" void kernel_launch(void* const* d_in, const int* in_sizes, int n_in,
                              void* d_out, int out_size, void* d_ws, size_t ws_size,
                              hipStream_t stream) {
    const float* x       = (const float*)d_in[0];
    const float* k_cache = (const float*)d_in[1];
    const float* v_cache = (const float*)d_in[2];
    const int*   kv_len  = (const int*)d_in[4];
    const float* qkv_w   = (const float*)d_in[6];
    const float* qkv_b   = (const float*)d_in[7];
    const float* out_w   = (const float*)d_in[8];
    const float* out_b   = (const float*)d_in[9];
    const float* ln1_w   = (const float*)d_in[10];
    const float* ln1_b   = (const float*)d_in[11];
    const float* ln2_w   = (const float*)d_in[12];
    const float* ln2_b   = (const float*)d_in[13];
    const float* mlp_w1  = (const float*)d_in[14];
    const float* mlp_b1  = (const float*)d_in[15];
    const float* mlp_w2  = (const float*)d_in[16];
    const float* mlp_b2  = (const float*)d_in[17];

    float* out = (float*)d_out;
    float* ws  = (float*)d_ws;
    float* qkv = ws;                  // 64*3072 = 196608
    float* o   = ws + 196608;         // 64*1024
    float* t2  = ws + 262144;         // 64*1024
    float* t3  = ws + 327680;         // 64*4096
    float* P   = ws + 589824;         // split-K partials
    // attention partials alias P (disjoint in time):
    float* m_ws = P;                          // 64*16*8 = 8192
    float* s_ws = P + 8192;                   // 8192
    float* o_ws = P + 16384;                  // 8192*64 = 524288

    // ---- qkv = x @ qkv_w + qkv_b : K=1024, KC=128 -> S=8 ----
    gemm64_part<128><<<dim3(48, 8), 256, 0, stream>>>(x, qkv_w, P, 1024, 3072);
    reduce_kernel<false><<<768, 256, 0, stream>>>(P, qkv_b, qkv, 3072, 8);

    // ---- attention (flash-decode over 8 chunks of 256, NT loads) ----
    attn_part<<<dim3(NB, NH, NC), 256, 0, stream>>>(qkv, k_cache, v_cache, kv_len, m_ws, s_ws, o_ws);
    attn_combine<<<dim3(NB, NH), 64, 0, stream>>>(m_ws, s_ws, o_ws, kv_len, o);

    // ---- t2 = LN1(x + o @ out_w + out_b) : K=1024, KC=64 -> S=16 (unchanged) 
    gemm64_part<64><<<dim3(16, 16), 256, 0, stream>>>(o, out_w, P, 1024, 1024);
    reduce_ln_kernel<16><<<64, 256, 0, stream>>>(P, out_b, x, ln1_w, ln1_b, t2);

    // ---- t3 = relu(t2 @ mlp_w1 + mlp_b1) : K=1024, KC=128 -> S=8 ----
    gemm64_part<128><<<dim3(64, 8), 256, 0, stream>>>(t2, mlp_w1, P, 1024, 4096);
    reduce_kernel<true><<<1024, 256, 0, stream>>>(P, mlp_b1, t3, 4096, 8);

    // ---- out = LN2(t2 + t3 @ mlp_w2 + mlp_b2) : K=4096, KC=128 -> S=32 ----
    gemm64_part<128><<<dim3(16, 32), 256, 0, stream>>>(t3, mlp_w2, P, 4096, 1024);
    reduce_ln_kernel<32><<<64, 256, 0, stream>>>(P, mlp_b2, t2, ln2_w, ln2_b, out);
}